// Round 2
// baseline (15936.125 us; speedup 1.0000x reference)
//
#include <hip/hip_runtime.h>
#include <math.h>

#define SEQ 1000
#define IND 76

__device__ __forceinline__ float sigf(float v) { return 1.0f / (1.0f + expf(-v)); }

// wreg layout (unioned across roles):
//  t<400: [0..37] w2 (L2 row t), [38..89] wSe (stage2-early 52), [90..141] wSl (stage2-late 52),
//         [142..169] wXe (dx-early 28), [170..197] wXl (dx-late 28)
//  t in [448,498): [0..127] w1 (L1 neuron, 4 rows x 32)
#define W2O 0
#define SEO 38
#define SLO 90
#define XEO 142
#define XLO 170

// Roles:
//  t<400:  slot group q=t>>2, c=t&3. L2 row t; stage2 slot (row = c<2 ? q : 100+q, half h=c&1);
//          dx slot (row q, chunk c). Lane c==0 owns m2[q], dx[q], liquid lm/lb/ls[q].
//  t<200:  rpart (readout partial, 1 FMA)
//  t in [400,419): xt prefetch (issue B0, write B2)
//  t in {420,421}: readout md owner
//  t in [424,432): r2 reduce (B2)
//  t in [448,498): L1 neuron n=t-448, pipelined one step ahead (exact R1 l1_step)
__global__ __launch_bounds__(512, 2) void dhsnn_fwd(
    const float* __restrict__ x,
    const float* __restrict__ W1, const float* __restrict__ b1,
    const float* __restrict__ tau_m1, const float* __restrict__ tau_n1,
    const float* __restrict__ W2, const float* __restrict__ b2,
    const float* __restrict__ tau_m2, const float* __restrict__ tau_n2,
    const float* __restrict__ Wxp, const float* __restrict__ bxp,
    const float* __restrict__ Wm, const float* __restrict__ bm,
    const float* __restrict__ Wa, const float* __restrict__ ba,
    const float* __restrict__ Wd, const float* __restrict__ bd,
    const float* __restrict__ tau_md,
    float* __restrict__ out)
{
    const int t   = (int)threadIdx.x;
    const int blk = (int)blockIdx.x;

    __shared__ __align__(16) float kin1P[128];    // [0..75] xt(j+1), [76..125] s1(j), [126..127]=0
    __shared__ __align__(16) float kin2P[4][40];  // branch windows of [s1(50), s2(100)]
    __shared__ __align__(16) float s1stage[56];
    __shared__ __align__(16) float s2P[104];      // s2 spikes (pad 100..103 = 0)
    __shared__ __align__(16) float dxP[104];
    __shared__ __align__(16) float lsP[104];
    __shared__ __align__(16) float lmP[104];
    __shared__ __align__(16) float lbP[104];
    __shared__ __align__(16) float rpart[200];
    __shared__ __align__(16) float r2[8];

    // ---- zero LDS ----
    for (int i = t; i < 128; i += 512) kin1P[i] = 0.f;
    for (int i = t; i < 160; i += 512) (&kin2P[0][0])[i] = 0.f;
    for (int i = t; i < 56;  i += 512) s1stage[i] = 0.f;
    for (int i = t; i < 104; i += 512) { s2P[i]=0.f; dxP[i]=0.f; lsP[i]=0.f; lmP[i]=0.f; lbP[i]=0.f; }
    for (int i = t; i < 200; i += 512) rpart[i] = 0.f;
    for (int i = t; i < 8;   i += 512) r2[i] = 0.f;

    const int q = t >> 2;      // neuron / row-group id (t<400)
    const int c = t & 3;       // lane within group
    const int h = c & 1;       // column half
    const int lbase = (t & 63) & ~3;

    float wreg[198];
    // sc: t<400: 0=b2,1=beta2; owner(c==0): 2=alpha2,3=bm,4=ba,5=bx; t<200: 6=wd
    //     L1: 0..3=b1, 4..7=beta1, 8=alpha1 ; md: 0=ad, 1=bd
    float sc[9];
    // st: t<400: 0=d2; owner: 1=m2, 2=s2spk, 3=lm, 4=lb, 5=ls, 6=dx
    //     L1: 0..3=d1, 4=m1, 5=s1spk
    float st[7];
    float eAcc = 0.f, dAcc = 0.f;      // stage2-early / dx-early partials (t<400)
    float mdr = 0.f, accr = 0.f;       // readout state (t=420,421)
    float4 xp0;
    int doff = 0;
    #pragma unroll
    for (int i = 0; i < 9; ++i) sc[i] = 0.f;
    #pragma unroll
    for (int i = 0; i < 7; ++i) st[i] = 0.f;

    // ---- weight / parameter init ----
    if (t < 400) {
        // L2 masked row t: branch c, cols [38c, min(38c+38,150))
        #pragma unroll
        for (int cc = 0; cc < 38; ++cc) {
            const int gc = 38 * c + cc;
            wreg[W2O + cc] = (gc < 150) ? W2[t * 150 + gc] : 0.f;
        }
        sc[0] = b2[t];
        sc[1] = sigf(tau_n2[t]);
        // stage2 slot: row = (c<2)? q (tauM/Wm) : 100+q (tauA/Wa); half h
        const float* Wrow = (c < 2) ? (Wm + q * 200) : (Wa + q * 200);
        const int eoff = h ? 52 : 0;
        #pragma unroll
        for (int u = 0; u < 52; ++u) {
            const int col = eoff + u;
            const bool ok = (col < 100);
            wreg[SEO + u] = ok ? Wrow[100 + col] : 0.f;  // mem (lm/lb) part
            wreg[SLO + u] = ok ? Wrow[col] : 0.f;        // dx part
        }
        // dx slot: row q, chunk c: c==0 -> cols 0..27 ; c>=1 -> 24 cols at 4+24c
        doff = (c == 0) ? 0 : (4 + 24 * c);
        const int dcnt = (c == 0) ? 28 : 24;
        #pragma unroll
        for (int u = 0; u < 28; ++u) {
            const int col = doff + u;
            const bool ok = (u < dcnt);
            wreg[XEO + u] = ok ? Wxp[q * 200 + 100 + col] : 0.f;  // ls part (cols 100..199)
            wreg[XLO + u] = ok ? Wxp[q * 200 + col] : 0.f;        // s2 part (cols 0..99)
        }
        if (c == 0) {
            sc[2] = sigf(tau_m2[q]);
            sc[3] = bm[q]; sc[4] = ba[q]; sc[5] = bxp[q];
            st[4] = 1.6f;                                 // lb init = b_j0
        }
        if (t < 200) sc[6] = Wd[(t < 100 ? 0 : 100) + (t % 100)];
    } else if (t >= 448 && t < 498) {
        const int n = t - 448;
        #pragma unroll
        for (int k = 0; k < 4; ++k) {
            #pragma unroll
            for (int u = 0; u < 32; ++u) {
                const int gc = 32 * k + u;
                wreg[k * 32 + u] = (gc < 126) ? W1[(4 * n + k) * 126 + gc] : 0.f;
            }
            sc[k]     = b1[4 * n + k];
            sc[4 + k] = sigf(tau_n1[4 * n + k]);
        }
        sc[8] = sigf(tau_m1[n]);
    } else if (t == 420 || t == 421) {
        sc[0] = sigf(tau_md[t - 420]);
        sc[1] = bd[t - 420];
    }

    // L1 step (exact R1 ordering): kin1P = [xt, s1_prev]
    auto l1_step = [&]() {
        float pr0 = sc[0], pr1 = sc[1], pr2 = sc[2], pr3 = sc[3];
        #pragma unroll
        for (int u4 = 0; u4 < 8; ++u4) {
            const float4 a0 = *reinterpret_cast<const float4*>(&kin1P[ 0 + 4 * u4]);
            const float4 a1 = *reinterpret_cast<const float4*>(&kin1P[32 + 4 * u4]);
            const float4 a2 = *reinterpret_cast<const float4*>(&kin1P[64 + 4 * u4]);
            const float4 a3 = *reinterpret_cast<const float4*>(&kin1P[96 + 4 * u4]);
            pr0 = fmaf(wreg[      4*u4+0], a0.x, pr0); pr0 = fmaf(wreg[      4*u4+1], a0.y, pr0);
            pr0 = fmaf(wreg[      4*u4+2], a0.z, pr0); pr0 = fmaf(wreg[      4*u4+3], a0.w, pr0);
            pr1 = fmaf(wreg[ 32 + 4*u4+0], a1.x, pr1); pr1 = fmaf(wreg[ 32 + 4*u4+1], a1.y, pr1);
            pr1 = fmaf(wreg[ 32 + 4*u4+2], a1.z, pr1); pr1 = fmaf(wreg[ 32 + 4*u4+3], a1.w, pr1);
            pr2 = fmaf(wreg[ 64 + 4*u4+0], a2.x, pr2); pr2 = fmaf(wreg[ 64 + 4*u4+1], a2.y, pr2);
            pr2 = fmaf(wreg[ 64 + 4*u4+2], a2.z, pr2); pr2 = fmaf(wreg[ 64 + 4*u4+3], a2.w, pr2);
            pr3 = fmaf(wreg[ 96 + 4*u4+0], a3.x, pr3); pr3 = fmaf(wreg[ 96 + 4*u4+1], a3.y, pr3);
            pr3 = fmaf(wreg[ 96 + 4*u4+2], a3.z, pr3); pr3 = fmaf(wreg[ 96 + 4*u4+3], a3.w, pr3);
        }
        const float d0 = sc[4] * st[0] + (1.f - sc[4]) * pr0;
        const float d1 = sc[5] * st[1] + (1.f - sc[5]) * pr1;
        const float d2 = sc[6] * st[2] + (1.f - sc[6]) * pr2;
        const float d3 = sc[7] * st[3] + (1.f - sc[7]) * pr3;
        st[0] = d0; st[1] = d1; st[2] = d2; st[3] = d3;
        const float sum = ((d0 + d1) + d2) + d3;
        st[4] = sc[8] * st[4] + (1.f - sc[8]) * sum - st[5];
        st[5] = (st[4] - 1.0f > 0.f) ? 1.f : 0.f;
        s1stage[t - 448] = st[5];
    };

    __syncthreads();
    if (t < 100) lbP[t] = 1.6f;
    if (t < 19) {
        const float4 v = *reinterpret_cast<const float4*>(x + (size_t)blk * SEQ * IND + 4 * t);
        *reinterpret_cast<float4*>(&kin1P[4 * t]) = v;   // xt(0)
    }
    __syncthreads();
    if (t >= 448 && t < 498) l1_step();   // L1 step 0 (s1(-1)=0)
    __syncthreads();
    if (t >= 128 && t < 178) {            // s1(0) -> kin buffers
        const int i2 = t - 128;
        const float v = s1stage[i2];
        kin1P[76 + i2] = v;
        const int w = i2 / 38;
        kin2P[w][i2 - 38 * w] = v;
    }
    if (t < 19) {                         // xt(1)
        const float4 v = *reinterpret_cast<const float4*>(x + ((size_t)blk * SEQ + 1) * IND + 4 * t);
        *reinterpret_cast<float4*>(&kin1P[4 * t]) = v;
    }
    __syncthreads();

    for (int j = 0; j < SEQ; ++j) {
        // ===== B0: L2(j)+s2 update, stage2-early(lm/lb), dx-early(ls), L1(j+1), rpart, prefetch =====
        if (t < 400) {
            {   // L2 row t (exact R1 ordering), then 4-lane gather -> m2/s2 at lane c==0
                const float* kw = kin2P[c];
                float a0 = 0.f, a1 = 0.f, a2 = 0.f, a3 = 0.f;
                #pragma unroll
                for (int cc = 0; cc < 9; ++cc) {
                    const float4 av = *reinterpret_cast<const float4*>(kw + 4 * cc);
                    a0 = fmaf(wreg[W2O + 4*cc + 0], av.x, a0);
                    a1 = fmaf(wreg[W2O + 4*cc + 1], av.y, a1);
                    a2 = fmaf(wreg[W2O + 4*cc + 2], av.z, a2);
                    a3 = fmaf(wreg[W2O + 4*cc + 3], av.w, a3);
                }
                a0 = fmaf(wreg[W2O + 36], kw[36], a0);
                a1 = fmaf(wreg[W2O + 37], kw[37], a1);
                const float proj = sc[0] + ((a0 + a1) + (a2 + a3));
                st[0] = sc[1] * st[0] + (1.f - sc[1]) * proj;     // d2
                const float dme = st[0];
                const float dd1 = __shfl(dme, lbase + 1, 64);
                const float dd2 = __shfl(dme, lbase + 2, 64);
                const float dd3 = __shfl(dme, lbase + 3, 64);
                if (c == 0) {
                    const float sum = ((dme + dd1) + dd2) + dd3;
                    st[1] = sc[2] * st[1] + (1.f - sc[2]) * sum - st[2];
                    st[2] = (st[1] - 1.0f > 0.f) ? 1.f : 0.f;
                    s2P[q] = st[2];
                }
            }
            {   // stage2-early over lm (c<2) or lb (c>=2), cols [52h, +52)
                const float* ap = ((c < 2) ? lmP : lbP) + (h ? 52 : 0);
                float e0=0.f, e1=0.f, e2=0.f, e3=0.f;
                #pragma unroll
                for (int u4 = 0; u4 < 13; ++u4) {
                    const float4 av = *reinterpret_cast<const float4*>(ap + 4 * u4);
                    e0 = fmaf(wreg[SEO + 4*u4 + 0], av.x, e0);
                    e1 = fmaf(wreg[SEO + 4*u4 + 1], av.y, e1);
                    e2 = fmaf(wreg[SEO + 4*u4 + 2], av.z, e2);
                    e3 = fmaf(wreg[SEO + 4*u4 + 3], av.w, e3);
                }
                eAcc = (e0 + e1) + (e2 + e3);
            }
            {   // dx-early over ls, chunk at doff
                const float* ap = lsP + doff;
                float f0=0.f, f1=0.f, f2=0.f, f3=0.f;
                #pragma unroll
                for (int u4 = 0; u4 < 7; ++u4) {
                    const float4 av = *reinterpret_cast<const float4*>(ap + 4 * u4);
                    f0 = fmaf(wreg[XEO + 4*u4 + 0], av.x, f0);
                    f1 = fmaf(wreg[XEO + 4*u4 + 1], av.y, f1);
                    f2 = fmaf(wreg[XEO + 4*u4 + 2], av.z, f2);
                    f3 = fmaf(wreg[XEO + 4*u4 + 3], av.w, f3);
                }
                dAcc = (f0 + f1) + (f2 + f3);
            }
            if (t < 200) rpart[t] = sc[6] * lsP[t % 100];   // readout partial over ls(j-1)
        } else if (t < 419) {
            if (j + 2 < SEQ)
                xp0 = *reinterpret_cast<const float4*>(x + ((size_t)blk * SEQ + (j + 2)) * IND + 4 * (t - 400));
        } else if (t >= 448 && t < 498) {
            if (j < SEQ - 1) l1_step();
        }
        __syncthreads();
        // ===== B2: dx-late over s2(j) -> dxP; kin2P s2 copy; r2 reduce; xt write =====
        if (t < 400) {
            const float* ap = s2P + doff;
            float f0=0.f, f1=0.f, f2=0.f, f3=0.f;
            #pragma unroll
            for (int u4 = 0; u4 < 7; ++u4) {
                const float4 av = *reinterpret_cast<const float4*>(ap + 4 * u4);
                f0 = fmaf(wreg[XLO + 4*u4 + 0], av.x, f0);
                f1 = fmaf(wreg[XLO + 4*u4 + 1], av.y, f1);
                f2 = fmaf(wreg[XLO + 4*u4 + 2], av.z, f2);
                f3 = fmaf(wreg[XLO + 4*u4 + 3], av.w, f3);
            }
            const float tot = ((f0 + f1) + (f2 + f3)) + dAcc;
            const float t1 = __shfl(tot, lbase + 1, 64);
            const float t2 = __shfl(tot, lbase + 2, 64);
            const float t3 = __shfl(tot, lbase + 3, 64);
            if (c == 0) {
                const float dxv = ((tot + t1) + (t2 + t3)) + sc[5];
                st[6] = dxv;
                dxP[q] = dxv;
                const int col = 50 + q;                       // s2 -> kin2P window copy
                const int w = (col >= 114) ? 3 : ((col >= 76) ? 2 : 1);
                kin2P[w][col - 38 * w] = st[2];
            }
        } else if (t < 419) {
            if (j + 2 < SEQ)
                *reinterpret_cast<float4*>(&kin1P[4 * (t - 400)]) = xp0;
        } else if (t >= 424 && t < 432) {
            const int rr = t - 424;
            float sV = 0.f;
            #pragma unroll
            for (int u = 0; u < 25; ++u) sV += rpart[25 * rr + u];
            r2[rr] = sV;
        }
        __syncthreads();
        // ===== B3: stage2-late over dx; gather -> sigmoids -> liquid update; copies; md =====
        if (t < 400) {
            const float* ap = dxP + (h ? 52 : 0);
            float e0=0.f, e1=0.f, e2=0.f, e3=0.f;
            #pragma unroll
            for (int u4 = 0; u4 < 13; ++u4) {
                const float4 av = *reinterpret_cast<const float4*>(ap + 4 * u4);
                e0 = fmaf(wreg[SLO + 4*u4 + 0], av.x, e0);
                e1 = fmaf(wreg[SLO + 4*u4 + 1], av.y, e1);
                e2 = fmaf(wreg[SLO + 4*u4 + 2], av.z, e2);
                e3 = fmaf(wreg[SLO + 4*u4 + 3], av.w, e3);
            }
            const float tot = ((e0 + e1) + (e2 + e3)) + eAcc;
            const float t1 = __shfl(tot, lbase + 1, 64);
            const float t2 = __shfl(tot, lbase + 2, 64);
            const float t3 = __shfl(tot, lbase + 3, 64);
            if (c == 0) {
                const float preM = (tot + t1) + sc[3];
                const float preA = (t2 + t3) + sc[4];
                const float tm = sigf(preM);
                const float ta = sigf(preA);
                const float lbN = ta * st[4] + (1.f - ta) * st[5];
                const float Bv  = 1.6f + 1.8f * lbN;
                const float lmN = st[3] * tm + (1.f - tm) * st[6] - Bv * st[5];
                const float lsN = (lmN - Bv > 0.f) ? 1.f : 0.f;
                st[3] = lmN; st[4] = lbN; st[5] = lsN;
                lmP[q] = lmN; lbP[q] = lbN; lsP[q] = lsN;
            }
        }
        if (t >= 128 && t < 178) {           // s1(j+1) -> kin buffers (for next B0)
            const int i2 = t - 128;
            const float v = s1stage[i2];
            kin1P[76 + i2] = v;
            const int w = i2 / 38;
            kin2P[w][i2 - 38 * w] = v;
        }
        if ((t == 420 || t == 421) && j >= 1) {
            const int o = t - 420;
            const float dot = ((r2[4*o] + r2[4*o+1]) + (r2[4*o+2] + r2[4*o+3])) + sc[1];
            mdr = sc[0] * mdr + (1.f - sc[0]) * dot;
            if (j >= 2) accr += mdr;
        }
        __syncthreads();
    }

    // ===== epilogue: readout of ls(SEQ-1) =====
    if (t < 200) rpart[t] = sc[6] * lsP[t % 100];
    __syncthreads();
    if (t >= 424 && t < 432) {
        const int rr = t - 424;
        float sV = 0.f;
        #pragma unroll
        for (int u = 0; u < 25; ++u) sV += rpart[25 * rr + u];
        r2[rr] = sV;
    }
    __syncthreads();
    if (t == 420 || t == 421) {
        const int o = t - 420;
        const float dot = ((r2[4*o] + r2[4*o+1]) + (r2[4*o+2] + r2[4*o+3])) + sc[1];
        mdr = sc[0] * mdr + (1.f - sc[0]) * dot;
        accr += mdr;
        out[blk * 2 + o] = accr;
    }
}

extern "C" void kernel_launch(void* const* d_in, const int* in_sizes, int n_in,
                              void* d_out, int out_size, void* d_ws, size_t ws_size,
                              hipStream_t stream) {
    const float* x      = (const float*)d_in[0];
    const float* W1     = (const float*)d_in[1];
    const float* b1     = (const float*)d_in[2];
    const float* tau_m1 = (const float*)d_in[3];
    const float* tau_n1 = (const float*)d_in[4];
    const float* W2     = (const float*)d_in[5];
    const float* b2     = (const float*)d_in[6];
    const float* tau_m2 = (const float*)d_in[7];
    const float* tau_n2 = (const float*)d_in[8];
    const float* Wx     = (const float*)d_in[9];
    const float* bx     = (const float*)d_in[10];
    const float* Wm     = (const float*)d_in[11];
    const float* bm     = (const float*)d_in[12];
    const float* Wa     = (const float*)d_in[13];
    const float* ba     = (const float*)d_in[14];
    const float* Wd     = (const float*)d_in[15];
    const float* bd     = (const float*)d_in[16];
    const float* tau_md = (const float*)d_in[17];
    float* out = (float*)d_out;

    const int batch = in_sizes[0] / (SEQ * IND);   // 256
    dhsnn_fwd<<<batch, 512, 0, stream>>>(x, W1, b1, tau_m1, tau_n1,
                                         W2, b2, tau_m2, tau_n2,
                                         Wx, bx, Wm, bm, Wa, ba,
                                         Wd, bd, tau_md, out);
}